// Round 1
// baseline (91.382 us; speedup 1.0000x reference)
//
#include <hip/hip_runtime.h>
#include <math.h>

#define BB 32
#define CC 512
#define CR 32
#define HWN 3136
#define HW4 784   // HWN / 4

// ---------------------------------------------------------------------------
// Kernel 1: per (b,c) plane-pair, one block of 256 threads:
//   - sum of xr plane, sum of xi plane  -> means ar, ai
//   - argmax over hw of score^2 = zr^2 + zi^2  (sqrt dropped: monotonic)
//   - gather fr,fi at argmax -> mr, mi
// ---------------------------------------------------------------------------
__global__ __launch_bounds__(256) void cg_reduce_kernel(
    const float* __restrict__ x,
    float* __restrict__ ar, float* __restrict__ ai,
    float* __restrict__ mr, float* __restrict__ mi)
{
    const int bc = blockIdx.x;            // 0 .. B*C-1
    const int b  = bc / CC;
    const int c  = bc % CC;
    const float* xr = x + (size_t)(b * 2 * CC + c) * HWN;
    const float* xi = x + (size_t)(b * 2 * CC + CC + c) * HWN;
    const float4* xr4 = (const float4*)xr;
    const float4* xi4 = (const float4*)xi;
    const int t = threadIdx.x;

    float sr = 0.0f, si = 0.0f;
    float bs = -1.0f;                     // best score^2 (scores are >= 0)
    int   bi = 0x7fffffff;

    for (int v = t; v < HW4; v += 256) {
        float4 r4 = xr4[v];
        float4 i4 = xi4[v];
        float fr[4] = { r4.x, r4.y, r4.z, r4.w };
        float fi[4] = { i4.x, i4.y, i4.z, i4.w };
#pragma unroll
        for (int k = 0; k < 4; ++k) {
            float r = fr[k], q = fi[k];
            sr += r; si += q;
            float d   = r * r + q * q;
            float inv = 1.0f / d;         // IEEE divide (no fast-math)
            float zr  = r + r * inv;
            float zi  = q - q * inv;
            float s   = zr * zr + zi * zi;
            int idx   = v * 4 + k;        // idx strictly increasing per thread
            if (s > bs) { bs = s; bi = idx; }
        }
    }

    // wave-level reduce (wave = 64)
#pragma unroll
    for (int off = 32; off > 0; off >>= 1) {
        sr += __shfl_down(sr, off);
        si += __shfl_down(si, off);
        float os = __shfl_down(bs, off);
        int   oi = __shfl_down(bi, off);
        if (os > bs || (os == bs && oi < bi)) { bs = os; bi = oi; }
    }

    __shared__ float lsr[4], lsi[4], lbs[4];
    __shared__ int   lbi[4];
    const int wave = t >> 6;
    if ((t & 63) == 0) { lsr[wave] = sr; lsi[wave] = si; lbs[wave] = bs; lbi[wave] = bi; }
    __syncthreads();

    if (t == 0) {
        sr = lsr[0]; si = lsi[0]; bs = lbs[0]; bi = lbi[0];
#pragma unroll
        for (int w = 1; w < 4; ++w) {
            sr += lsr[w]; si += lsi[w];
            if (lbs[w] > bs || (lbs[w] == bs && lbi[w] < bi)) { bs = lbs[w]; bi = lbi[w]; }
        }
        ar[bc] = sr * (1.0f / HWN);
        ai[bc] = si * (1.0f / HWN);
        mr[bc] = xr[bi];
        mi[bc] = xi[bi];
    }
}

// ---------------------------------------------------------------------------
// Kernel 2: both complex MLPs + sum, one block per batch row.
//   att = MLP(ar,ai) + MLP(mr,mi);  out[b, 0:C] = re, out[b, C:2C] = im
// ---------------------------------------------------------------------------
__global__ __launch_bounds__(256) void cg_mlp_kernel(
    const float* __restrict__ ar, const float* __restrict__ ai,
    const float* __restrict__ mr, const float* __restrict__ mi,
    const float* __restrict__ w1r, const float* __restrict__ b1r,
    const float* __restrict__ w1i, const float* __restrict__ b1i,
    const float* __restrict__ w2r, const float* __restrict__ b2r,
    const float* __restrict__ w2i, const float* __restrict__ b2i,
    float* __restrict__ out)
{
    __shared__ float s_re[2][CC], s_im[2][CC];
    __shared__ float h_re[2][CR], h_im[2][CR];

    const int b = blockIdx.x;
    const int t = threadIdx.x;

    for (int k = t; k < CC; k += 256) {
        s_re[0][k] = ar[b * CC + k];
        s_im[0][k] = ai[b * CC + k];
        s_re[1][k] = mr[b * CC + k];
        s_im[1][k] = mi[b * CC + k];
    }
    __syncthreads();

    // ---- layer 1 + cardioid: 64 tasks (m,j), 4 threads per task ----
    {
        const int task = t >> 2;          // 0..63
        const int part = t & 3;
        const int m = task >> 5;          // 0..1  (which MLP input)
        const int j = task & 31;          // hidden unit
        const float* wr = w1r + j * CC;
        const float* wi = w1i + j * CC;
        float d_rr = 0.f, d_ir = 0.f, d_ri = 0.f, d_ii = 0.f;
        const int k0 = part * 128;
        for (int k = k0; k < k0 + 128; ++k) {
            float re = s_re[m][k], im = s_im[m][k];
            float vr = wr[k], vi = wi[k];
            d_rr += re * vr;              // re . w1r[j]
            d_ir += im * vr;              // im . w1r[j]
            d_ri += re * vi;              // re . w1i[j]
            d_ii += im * vi;              // im . w1i[j]
        }
        d_rr += __shfl_xor(d_rr, 1); d_rr += __shfl_xor(d_rr, 2);
        d_ir += __shfl_xor(d_ir, 1); d_ir += __shfl_xor(d_ir, 2);
        d_ri += __shfl_xor(d_ri, 1); d_ri += __shfl_xor(d_ri, 2);
        d_ii += __shfl_xor(d_ii, 1); d_ii += __shfl_xor(d_ii, 2);
        if (part == 0) {
            float hre = d_rr + b1r[j] - d_ii - b1i[j];
            float him = d_ir + b1r[j] + d_ri + b1i[j];
            // cardioid: s = 0.5*(1 + cos(atan2(im,re))) = 0.5*(1 + re/|z|)
            float n2 = hre * hre + him * him;
            float s  = (n2 > 0.0f) ? 0.5f * (1.0f + hre * rsqrtf(n2)) : 1.0f;
            h_re[m][j] = hre * s;
            h_im[m][j] = him * s;
        }
    }
    __syncthreads();

    // ---- layer 2 (summed over both MLPs) ----
    for (int j = t; j < CC; j += 256) {
        float o_re = 2.0f * (b2r[j] - b2i[j]);   // bias applied per MLP (x2)
        float o_im = 2.0f * (b2r[j] + b2i[j]);
        const float* wr = w2r + j * CR;
        const float* wi = w2i + j * CR;
#pragma unroll
        for (int m = 0; m < 2; ++m) {
#pragma unroll
            for (int k = 0; k < CR; ++k) {
                float hr = h_re[m][k], hi = h_im[m][k];
                float vr = wr[k], vi = wi[k];
                o_re += hr * vr - hi * vi;
                o_im += hi * vr + hr * vi;
            }
        }
        out[b * 2 * CC + j]      = o_re;
        out[b * 2 * CC + CC + j] = o_im;
    }
}

extern "C" void kernel_launch(void* const* d_in, const int* in_sizes, int n_in,
                              void* d_out, int out_size, void* d_ws, size_t ws_size,
                              hipStream_t stream)
{
    const float* x   = (const float*)d_in[0];
    const float* w1r = (const float*)d_in[1];
    const float* b1r = (const float*)d_in[2];
    const float* w1i = (const float*)d_in[3];
    const float* b1i = (const float*)d_in[4];
    const float* w2r = (const float*)d_in[5];
    const float* b2r = (const float*)d_in[6];
    const float* w2i = (const float*)d_in[7];
    const float* b2i = (const float*)d_in[8];

    float* ws = (float*)d_ws;
    float* ar = ws;
    float* ai = ws + BB * CC;
    float* mr = ws + 2 * BB * CC;
    float* mi = ws + 3 * BB * CC;

    cg_reduce_kernel<<<BB * CC, 256, 0, stream>>>(x, ar, ai, mr, mi);
    cg_mlp_kernel<<<BB, 256, 0, stream>>>(ar, ai, mr, mi,
                                          w1r, b1r, w1i, b1i,
                                          w2r, b2r, w2i, b2i,
                                          (float*)d_out);
}

// Round 3
// 78.632 us; speedup vs baseline: 1.1621x; 1.1621x over previous
//
#include <hip/hip_runtime.h>
#include <math.h>

#define BB 32
#define CC 512
#define CR 32
#define HWN 3136
#define HW4 784   // HWN / 4

typedef float f32x4 __attribute__((ext_vector_type(4)));

// ---------------------------------------------------------------------------
// Kernel 1: per (b,c) plane-pair, one block of 256 threads:
//   - sum of xr plane, sum of xi plane  -> means ar, ai
//   - argmax over hw of score^2 = zr^2 + zi^2  (sqrt dropped: monotonic)
//   - gather fr,fi at argmax -> mr, mi
//
// score^2 = d + 2(r^2-q^2)/d + d/d^2  where d = r^2+q^2
//         = fma(fma(d,u, 2(r^2-q^2)), u, d)  with u = 1/d  (fast rcp: argmax
//           only — output values are exact gathers, 1-ulp rcp can't flip a
//           non-degenerate argmax)
// ---------------------------------------------------------------------------
__global__ __launch_bounds__(256) void cg_reduce_kernel(
    const float* __restrict__ x,
    float* __restrict__ ar, float* __restrict__ ai,
    float* __restrict__ mr, float* __restrict__ mi)
{
    const int bc = blockIdx.x;            // 0 .. B*C-1
    const int b  = bc / CC;
    const int c  = bc % CC;
    const float* xr = x + (size_t)(b * 2 * CC + c) * HWN;
    const float* xi = x + (size_t)(b * 2 * CC + CC + c) * HWN;
    const f32x4* xr4 = (const f32x4*)xr;
    const f32x4* xi4 = (const f32x4*)xi;
    const int t = threadIdx.x;

    float sr = 0.0f, si = 0.0f;
    float bs = -1.0f;                     // best score^2 (scores are >= 0)
    int   bi = 0x7fffffff;

    for (int v = t; v < HW4; v += 256) {
        f32x4 r4 = __builtin_nontemporal_load(&xr4[v]);
        f32x4 i4 = __builtin_nontemporal_load(&xi4[v]);
#pragma unroll
        for (int k = 0; k < 4; ++k) {
            float r = r4[k], q = i4[k];
            sr += r; si += q;
            float r2 = r * r;
            float q2 = q * q;
            float d  = r2 + q2;
            float u  = __builtin_amdgcn_rcpf(d);          // ~1 ulp
            float s  = fmaf(fmaf(d, u, 2.0f * (r2 - q2)), u, d);
            int idx  = v * 4 + k;         // idx strictly increasing per thread
            if (s > bs) { bs = s; bi = idx; }
        }
    }

    // wave-level reduce (wave = 64)
#pragma unroll
    for (int off = 32; off > 0; off >>= 1) {
        sr += __shfl_down(sr, off);
        si += __shfl_down(si, off);
        float os = __shfl_down(bs, off);
        int   oi = __shfl_down(bi, off);
        if (os > bs || (os == bs && oi < bi)) { bs = os; bi = oi; }
    }

    __shared__ float lsr[4], lsi[4], lbs[4];
    __shared__ int   lbi[4];
    const int wave = t >> 6;
    if ((t & 63) == 0) { lsr[wave] = sr; lsi[wave] = si; lbs[wave] = bs; lbi[wave] = bi; }
    __syncthreads();

    if (t == 0) {
        sr = lsr[0]; si = lsi[0]; bs = lbs[0]; bi = lbi[0];
#pragma unroll
        for (int w = 1; w < 4; ++w) {
            sr += lsr[w]; si += lsi[w];
            if (lbs[w] > bs || (lbs[w] == bs && lbi[w] < bi)) { bs = lbs[w]; bi = lbi[w]; }
        }
        ar[bc] = sr * (1.0f / HWN);
        ai[bc] = si * (1.0f / HWN);
        mr[bc] = xr[bi];
        mi[bc] = xi[bi];
    }
}

// ---------------------------------------------------------------------------
// Kernel 2: both complex MLPs + sum, one block per batch row.
//   att = MLP(ar,ai) + MLP(mr,mi);  out[b, 0:C] = re, out[b, C:2C] = im
// ---------------------------------------------------------------------------
__global__ __launch_bounds__(256) void cg_mlp_kernel(
    const float* __restrict__ ar, const float* __restrict__ ai,
    const float* __restrict__ mr, const float* __restrict__ mi,
    const float* __restrict__ w1r, const float* __restrict__ b1r,
    const float* __restrict__ w1i, const float* __restrict__ b1i,
    const float* __restrict__ w2r, const float* __restrict__ b2r,
    const float* __restrict__ w2i, const float* __restrict__ b2i,
    float* __restrict__ out)
{
    __shared__ float s_re[2][CC], s_im[2][CC];
    __shared__ float h_re[2][CR], h_im[2][CR];

    const int b = blockIdx.x;
    const int t = threadIdx.x;

    for (int k = t; k < CC; k += 256) {
        s_re[0][k] = ar[b * CC + k];
        s_im[0][k] = ai[b * CC + k];
        s_re[1][k] = mr[b * CC + k];
        s_im[1][k] = mi[b * CC + k];
    }
    __syncthreads();

    // ---- layer 1 + cardioid: 64 tasks (m,j), 4 threads per task ----
    {
        const int task = t >> 2;          // 0..63
        const int part = t & 3;
        const int m = task >> 5;          // 0..1  (which MLP input)
        const int j = task & 31;          // hidden unit
        const float* wr = w1r + j * CC;
        const float* wi = w1i + j * CC;
        float d_rr = 0.f, d_ir = 0.f, d_ri = 0.f, d_ii = 0.f;
        const int k0 = part * 128;
        for (int k = k0; k < k0 + 128; ++k) {
            float re = s_re[m][k], im = s_im[m][k];
            float vr = wr[k], vi = wi[k];
            d_rr += re * vr;              // re . w1r[j]
            d_ir += im * vr;              // im . w1r[j]
            d_ri += re * vi;              // re . w1i[j]
            d_ii += im * vi;              // im . w1i[j]
        }
        d_rr += __shfl_xor(d_rr, 1); d_rr += __shfl_xor(d_rr, 2);
        d_ir += __shfl_xor(d_ir, 1); d_ir += __shfl_xor(d_ir, 2);
        d_ri += __shfl_xor(d_ri, 1); d_ri += __shfl_xor(d_ri, 2);
        d_ii += __shfl_xor(d_ii, 1); d_ii += __shfl_xor(d_ii, 2);
        if (part == 0) {
            float hre = d_rr + b1r[j] - d_ii - b1i[j];
            float him = d_ir + b1r[j] + d_ri + b1i[j];
            // cardioid: s = 0.5*(1 + cos(atan2(im,re))) = 0.5*(1 + re/|z|)
            float n2 = hre * hre + him * him;
            float s  = (n2 > 0.0f) ? 0.5f * (1.0f + hre * rsqrtf(n2)) : 1.0f;
            h_re[m][j] = hre * s;
            h_im[m][j] = him * s;
        }
    }
    __syncthreads();

    // ---- layer 2 (summed over both MLPs) ----
    for (int j = t; j < CC; j += 256) {
        float o_re = 2.0f * (b2r[j] - b2i[j]);   // bias applied per MLP (x2)
        float o_im = 2.0f * (b2r[j] + b2i[j]);
        const float* wr = w2r + j * CR;
        const float* wi = w2i + j * CR;
#pragma unroll
        for (int m = 0; m < 2; ++m) {
#pragma unroll
            for (int k = 0; k < CR; ++k) {
                float hr = h_re[m][k], hi = h_im[m][k];
                float vr = wr[k], vi = wi[k];
                o_re += hr * vr - hi * vi;
                o_im += hi * vr + hr * vi;
            }
        }
        out[b * 2 * CC + j]      = o_re;
        out[b * 2 * CC + CC + j] = o_im;
    }
}

extern "C" void kernel_launch(void* const* d_in, const int* in_sizes, int n_in,
                              void* d_out, int out_size, void* d_ws, size_t ws_size,
                              hipStream_t stream)
{
    const float* x   = (const float*)d_in[0];
    const float* w1r = (const float*)d_in[1];
    const float* b1r = (const float*)d_in[2];
    const float* w1i = (const float*)d_in[3];
    const float* b1i = (const float*)d_in[4];
    const float* w2r = (const float*)d_in[5];
    const float* b2r = (const float*)d_in[6];
    const float* w2i = (const float*)d_in[7];
    const float* b2i = (const float*)d_in[8];

    float* ws = (float*)d_ws;
    float* ar = ws;
    float* ai = ws + BB * CC;
    float* mr = ws + 2 * BB * CC;
    float* mi = ws + 3 * BB * CC;

    cg_reduce_kernel<<<BB * CC, 256, 0, stream>>>(x, ar, ai, mr, mi);
    cg_mlp_kernel<<<BB, 256, 0, stream>>>(ar, ai, mr, mi,
                                          w1r, b1r, w1i, b1i,
                                          w2r, b2r, w2i, b2i,
                                          (float*)d_out);
}